// Round 12
// baseline (199.751 us; speedup 1.0000x reference)
//
#include <hip/hip_runtime.h>
#include <hip/hip_bf16.h>
#include <math.h>

// Problem constants (SchNet reference)
#define NATOMS 16384
#define NMOL   512
#define APM    32
#define GDIM   50
#define KTAB   2048   // filter lookup-table knots over d in [0,6]
#define MAXEPM 1000   // max edges per molecule (992) + sentinel

#define STRH 132      // s_h / s_hx row stride (floats), 528B; %32=4 rotates banks
#define STRA 136      // s_agg / s_t row stride (ushorts), 272B

typedef __attribute__((ext_vector_type(8))) short   short8;   // 8 bf16 (A/B frag)
typedef __attribute__((ext_vector_type(4))) float   floatx4;  // C/D frag

// fast shifted softplus: log(1+exp(x)) - log2, via HW v_exp_f32/v_log_f32
__device__ __forceinline__ float ssp(float x) {
    float e = __expf(-fabsf(x));
    return fmaxf(x, 0.0f) + __logf(1.0f + e) - 0.69314718055994531f;
}

__device__ __forceinline__ unsigned short f2bf(float x) {
    union { float f; unsigned int u; } v; v.f = x;
    unsigned int lsb = (v.u >> 16) & 1u;
    v.u += 0x7fffu + lsb;
    return (unsigned short)(v.u >> 16);
}

__device__ __forceinline__ float bf2f(unsigned int u16bits) {
    union { unsigned int u; float f; } v; v.u = u16bits << 16;
    return v.f;
}

__device__ __forceinline__ unsigned int pk2bf(float a, float b) {
    __hip_bfloat162 h = __float22bfloat162_rn(make_float2(a, b));
    unsigned int u;
    __builtin_memcpy(&u, &h, 4);
    return u;
}

// ---------------------------------------------------------------------------
// MEGA-SETUP (single dispatch, 3 block regions):
//  [0,EB):        per-edge meta {knot<<6 | dst&31, frac} + rowptr
//  [EB,EB+WB):    weights fp32 -> bf16 B-frag transpose (9x128x128 + out1 64x128)
//  [EB+WB, +99):  filter table, 33 tiles x 3 layers; tiles overlap by 1 knot
//                 and write packed Tp = (w0 | bf16(T[k+1]-T[k])<<16) directly.
// ---------------------------------------------------------------------------
#define KW1 72
#define KW2 136
#define TILE_K 63     // knots advanced per table tile (64 computed, 63 written)
#define NTILE 33      // ceil((KTAB-1)/63)

__global__ __launch_bounds__(256) void mega_setup_kernel(
    const float* __restrict__ pos, const int* __restrict__ eidx, int E, int EB,
    int* __restrict__ rowptr,
    const float* __restrict__ cf1, const float* __restrict__ cf2,
    const float* __restrict__ lin, const float* __restrict__ out1,
    unsigned short* __restrict__ Wtall, uint2* __restrict__ meta,
    const float* __restrict__ w1_, const float* __restrict__ b1_,
    const float* __restrict__ w2_, const float* __restrict__ b2_,
    unsigned int* __restrict__ Tp)
{
    const int WB = (9 * 16384 + 64 * 128 + 255) / 256;
    const int b = blockIdx.x;
    const int tid = threadIdx.x;

    if (b < EB) {
        int idx = b * 256 + tid;
        if (idx < E) {
            int s = eidx[idx], t = eidx[E + idx];
            float dx = pos[3 * s]     - pos[3 * t];
            float dy = pos[3 * s + 1] - pos[3 * t + 1];
            float dz = pos[3 * s + 2] - pos[3 * t + 2];
            float d  = sqrtf(dx * dx + dy * dy + dz * dz);
            float u  = d * (float)(KTAB - 1) / 6.0f;
            int i = min((int)u, KTAB - 2);
            meta[idx] = make_uint2(((unsigned)i << 6) | (unsigned)(t & 31),
                                   __float_as_uint(u - (float)i));
        } else if (idx < E + NATOMS + 1) {
            int a = idx - E;
            int lo = 0, hi = E;
            while (lo < hi) { int mid = (lo + hi) >> 1; if (eidx[mid] < a) lo = mid + 1; else hi = mid; }
            rowptr[a] = lo;
        }
        return;
    }
    if (b < EB + WB) {
        int idx = (b - EB) * 256 + tid;
        if (idx < 9 * 16384) {
            int wi = idx >> 14, rem = idx & 16383;
            int n = rem >> 7, k = rem & 127;
            int l = wi / 3, which = wi % 3;
            const float* src = (which == 0) ? cf1 : (which == 1) ? cf2 : lin;
            Wtall[idx] = f2bf(src[(size_t)l * 16384 + k * 128 + n]);
        } else if (idx < 9 * 16384 + 64 * 128) {
            int q = idx - 9 * 16384;
            int n = q >> 7, k = q & 127;
            Wtall[idx] = f2bf(out1[k * 64 + n]);
        }
        return;
    }

    // ---------------- table region: tt = (layer, tile) ----------------
    __shared__ unsigned short s_bufA[128 * KW2];   // w2T
    __shared__ unsigned short s_bufB[128 * KW1];   // w1T, then s_t / T_lds (alias)

    const int tt = b - EB - WB;
    const int l  = tt / NTILE;
    const int bx = tt % NTILE;
    const float* w1 = w1_ + (size_t)l * GDIM * 128;
    const float* b1 = b1_ + (size_t)l * 128;
    const float* w2 = w2_ + (size_t)l * 128 * 128;
    const float* b2 = b2_ + (size_t)l * 128;
    unsigned int* Tpg = Tp + (size_t)l * KTAB * 128;

    unsigned short* s_w1T = s_bufB;                // [128][KW1]
    unsigned short* s_w2T = s_bufA;                // [128][KW2]
    unsigned short* s_t   = s_bufB;                // [64][KW2] (after barrier)

    for (int i = tid; i < GDIM * 128; i += 256) {
        int g = i >> 7, f = i & 127;
        s_w1T[f * KW1 + g] = f2bf(w1[i]);
    }
    for (int i = tid; i < (64 - GDIM) * 128; i += 256) {
        int g = GDIM + (i >> 7), f = i & 127;
        s_w1T[f * KW1 + g] = 0;
    }
    for (int i = tid; i < 128 * 128; i += 256) {
        int k = i >> 7, n = i & 127;
        s_w2T[n * KW2 + k] = f2bf(w2[i]);
    }

    const int lane = tid & 63;
    const int w    = tid >> 6;
    const int l15  = lane & 15;
    const int quad = lane >> 4;

    float b1v[8], b2v[8];
    #pragma unroll
    for (int nt = 0; nt < 8; nt++) {
        b1v[nt] = b1[nt * 16 + l15];
        b2v[nt] = b2[nt * 16 + l15];
    }
    __syncthreads();

    const float hstep = 6.0f / (float)(KTAB - 1);
    const float step  = 6.0f / 49.0f;
    const float coeff = -0.5f / (step * step);
    const float pioc  = 3.14159265358979323846f / 6.0f;
    const int k0 = bx * TILE_K;
    const float dm = (float)(k0 + w * 16 + l15) * hstep;

    floatx4 acc1[8];
    #pragma unroll
    for (int nt = 0; nt < 8; nt++) acc1[nt] = (floatx4){0.f, 0.f, 0.f, 0.f};
    #pragma unroll
    for (int ks = 0; ks < 2; ks++) {
        unsigned int ap[4];
        #pragma unroll
        for (int jj = 0; jj < 4; jj++) {
            int g0 = ks * 32 + quad * 8 + 2 * jj;
            float d0 = dm - (float)g0 * step;
            float d1 = dm - (float)(g0 + 1) * step;
            float v0 = (g0 < GDIM)     ? __expf(coeff * d0 * d0) : 0.0f;
            float v1 = (g0 + 1 < GDIM) ? __expf(coeff * d1 * d1) : 0.0f;
            ap[jj] = pk2bf(v0, v1);
        }
        short8 af;
        __builtin_memcpy(&af, ap, 16);
        #pragma unroll
        for (int nt = 0; nt < 8; nt++) {
            short8 bfg = *(const short8*)&s_w1T[(nt * 16 + l15) * KW1 + ks * 32 + quad * 8];
            acc1[nt] = __builtin_amdgcn_mfma_f32_16x16x32_bf16(af, bfg, acc1[nt], 0, 0, 0);
        }
    }
    __syncthreads();   // all waves done reading s_w1T; s_t may alias it

    #pragma unroll
    for (int nt = 0; nt < 8; nt++) {
        #pragma unroll
        for (int r = 0; r < 4; r++) {
            int row = w * 16 + quad * 4 + r;
            s_t[row * KW2 + nt * 16 + l15] = f2bf(ssp(acc1[nt][r] + b1v[nt]));
        }
    }
    // no barrier: wave reads only rows it wrote

    floatx4 acc2[8];
    #pragma unroll
    for (int nt = 0; nt < 8; nt++) acc2[nt] = (floatx4){0.f, 0.f, 0.f, 0.f};
    #pragma unroll
    for (int ks = 0; ks < 4; ks++) {
        short8 af = *(const short8*)&s_t[(w * 16 + l15) * KW2 + ks * 32 + quad * 8];
        #pragma unroll
        for (int nt = 0; nt < 8; nt++) {
            short8 bfg = *(const short8*)&s_w2T[(nt * 16 + l15) * KW2 + ks * 32 + quad * 8];
            acc2[nt] = __builtin_amdgcn_mfma_f32_16x16x32_bf16(af, bfg, acc2[nt], 0, 0, 0);
        }
    }

    unsigned short* T_lds = s_t;
    #pragma unroll
    for (int nt = 0; nt < 8; nt++) {
        #pragma unroll
        for (int r = 0; r < 4; r++) {
            int row = w * 16 + quad * 4 + r;
            float d = (float)(k0 + row) * hstep;
            float cut = 0.5f * (__cosf(d * pioc) + 1.0f);
            T_lds[row * KW2 + nt * 16 + l15] = f2bf((acc2[nt][r] + b2v[nt]) * cut);
        }
    }
    __syncthreads();

    for (int i = tid; i < TILE_K * 128; i += 256) {
        int r = i >> 7, f = i & 127;
        int k = k0 + r;
        if (k <= KTAB - 2) {
            unsigned int w0 = T_lds[r * KW2 + f];
            unsigned int w1b = T_lds[(r + 1) * KW2 + f];
            unsigned int dw = f2bf(bf2f(w1b) - bf2f(w0));
            Tpg[(size_t)k * 128 + f] = w0 | (dw << 16);
        }
    }
}

// ---------------------------------------------------------------------------
// Fully-fused SchNet: one block = one molecule, 512 threads = 8 waves.
// GEMM tile per wave: rows (w&1)*16, cols (w>>1)*32.
// GATHER (transposed): wave w owns channels [w*16,w*16+16); lane's atom =
// lane&31, half-wave pair splits each atom's edges by parity. All 32 atoms
// advance in parallel; serial steps = ceil(maxdeg/2). Tp row slice (64B)
// double-buffered one step ahead; hx from LDS (132-stride rotates banks).
// One cross-pair combine + one s_agg write per layer.
// ---------------------------------------------------------------------------
__global__ __launch_bounds__(512, 4) void fused_schnet_kernel(
    const int* __restrict__ z, const float* __restrict__ emb,
    const int* __restrict__ rowptr, const uint2* __restrict__ meta,
    const unsigned int* __restrict__ Tp,
    const unsigned short* __restrict__ Wtall,
    const float* __restrict__ cf2_b, const float* __restrict__ lin_b,
    const float* __restrict__ out1_b, const float* __restrict__ out2_w,
    const float* __restrict__ out2_b,
    float* __restrict__ out)
{
    __shared__ float s_h[32 * STRH];                 // 16.9 KB fp32 node state
    __shared__ float s_hx[33 * STRH];                // 17.4 KB; row 32 = zeros
    __shared__ unsigned short s_agg[32 * STRA];      //  8.7 KB bf16
    __shared__ uint2 s_meta[MAXEPM];                 //  8.0 KB
    __shared__ float s_red;
    unsigned short* s_t = (unsigned short*)s_hx;     // [32][STRA] alias (8.7KB)

    const int tid  = threadIdx.x;
    const int lane = tid & 63;
    const int w    = tid >> 6;          // wave 0..7
    const int l15  = lane & 15;
    const int quad = lane >> 4;
    const int r16  = (w & 1) * 16;      // GEMM row tile
    const int c32  = (w >> 1) * 32;     // GEMM col tile
    const int cw   = w * 16;            // gather channel slice
    const int atom = lane & 31;         // gather atom
    const int pair = lane >> 5;         // edge parity
    const int B0   = blockIdx.x * 32;   // molecule base atom

    // init h; zero hx dummy row
    for (int i = tid; i < 32 * 128; i += 512) {
        int row = i >> 7, col = i & 127;
        s_h[row * STRH + col] = emb[(size_t)z[B0 + row] * 128 + col];
    }
    if (tid < 128) s_hx[32 * STRH + tid] = 0.0f;
    if (tid == 0) s_red = 0.0f;

    // stage edge metadata + sentinel (points at zero row 32, fr=0)
    const int ebase = rowptr[B0];
    const int nE    = rowptr[B0 + 32] - ebase;
    for (int i = tid; i < nE; i += 512) s_meta[i] = meta[ebase + i];
    if (tid == 0) s_meta[nE] = make_uint2(32u, 0u);

    // rowptr for atoms (lanes 0..32 hold bounds)
    const int rp = rowptr[B0 + min(lane, 32)] - ebase;
    const int e0 = __shfl(rp, atom);
    const int e1 = __shfl(rp, atom + 1);
    // wave-max degree -> uniform round count
    int md = e1 - e0;
    #pragma unroll
    for (int off = 1; off < 32; off <<= 1) md = max(md, __shfl_xor(md, off));
    const int rounds = (md + 1) >> 1;

    const unsigned short* WtO = Wtall + 9 * 16384;   // out1^T

    for (int l = 0; l < 3; l++) {
        const unsigned short* W1 = Wtall + (size_t)(l * 3 + 0) * 16384;
        const unsigned short* W2 = Wtall + (size_t)(l * 3 + 1) * 16384;
        const unsigned short* W3 = Wtall + (size_t)(l * 3 + 2) * 16384;
        const unsigned int* Tpl  = Tp + (size_t)l * KTAB * 128;

        __syncthreads();   // h ready (also covers init/meta staging at l=0)

        // ---- GEMM1: hx = h @ cf1 (16x32 tile per wave) ----
        floatx4 acc[2];
        #pragma unroll
        for (int nt = 0; nt < 2; nt++) acc[nt] = (floatx4){0.f, 0.f, 0.f, 0.f};
        #pragma unroll
        for (int ks = 0; ks < 4; ks++) {
            const float* hp = &s_h[(r16 + l15) * STRH + ks * 32 + quad * 8];
            float4 xa = *(const float4*)hp;
            float4 xb = *(const float4*)(hp + 4);
            unsigned int ap[4];
            ap[0] = pk2bf(xa.x, xa.y); ap[1] = pk2bf(xa.z, xa.w);
            ap[2] = pk2bf(xb.x, xb.y); ap[3] = pk2bf(xb.z, xb.w);
            short8 af;
            __builtin_memcpy(&af, ap, 16);
            #pragma unroll
            for (int nt = 0; nt < 2; nt++) {
                short8 bfg = *(const short8*)&W1[(size_t)(c32 + nt * 16 + l15) * 128 + ks * 32 + quad * 8];
                acc[nt] = __builtin_amdgcn_mfma_f32_16x16x32_bf16(af, bfg, acc[nt], 0, 0, 0);
            }
        }
        #pragma unroll
        for (int nt = 0; nt < 2; nt++) {
            #pragma unroll
            for (int r = 0; r < 4; r++)
                s_hx[(r16 + quad * 4 + r) * STRH + c32 + nt * 16 + l15] = acc[nt][r];
        }

        __syncthreads();   // hx complete before gather reads

        // ---- transposed gather: lane=atom, 16 channels, parity-split ----
        float ga[16];
        #pragma unroll
        for (int i = 0; i < 16; i++) ga[i] = 0.0f;
        {
            int e = e0 + pair;
            int idx = (e < e1) ? e : nE;
            uint2 q = s_meta[idx];
            uint4 t0 = *(const uint4*)&Tpl[(size_t)(q.x >> 6) * 128 + cw];
            uint4 t1 = *(const uint4*)&Tpl[(size_t)(q.x >> 6) * 128 + cw + 4];
            uint4 t2 = *(const uint4*)&Tpl[(size_t)(q.x >> 6) * 128 + cw + 8];
            uint4 t3 = *(const uint4*)&Tpl[(size_t)(q.x >> 6) * 128 + cw + 12];
            for (int r = 0; r < rounds; r++) {
                // prefetch next step
                int en = e + 2;
                int idxn = (en < e1) ? en : nE;
                uint2 qn = s_meta[idxn];
                uint4 n0 = *(const uint4*)&Tpl[(size_t)(qn.x >> 6) * 128 + cw];
                uint4 n1 = *(const uint4*)&Tpl[(size_t)(qn.x >> 6) * 128 + cw + 4];
                uint4 n2 = *(const uint4*)&Tpl[(size_t)(qn.x >> 6) * 128 + cw + 8];
                uint4 n3 = *(const uint4*)&Tpl[(size_t)(qn.x >> 6) * 128 + cw + 12];
                // accumulate current
                int tl = q.x & 63;
                float fr = __uint_as_float(q.y);
                const float* hp = &s_hx[tl * STRH + cw];
                float4 h0 = *(const float4*)hp;
                float4 h1 = *(const float4*)(hp + 4);
                float4 h2 = *(const float4*)(hp + 8);
                float4 h3 = *(const float4*)(hp + 12);
                unsigned int tu[16];
                *(uint4*)&tu[0] = t0; *(uint4*)&tu[4] = t1;
                *(uint4*)&tu[8] = t2; *(uint4*)&tu[12] = t3;
                float hv[16];
                *(float4*)&hv[0] = h0; *(float4*)&hv[4] = h1;
                *(float4*)&hv[8] = h2; *(float4*)&hv[12] = h3;
                #pragma unroll
                for (int i = 0; i < 16; i++) {
                    float wv = fmaf(fr, __uint_as_float(tu[i] & 0xffff0000u),
                                    __uint_as_float(tu[i] << 16));
                    ga[i] = fmaf(hv[i], wv, ga[i]);
                }
                q = qn; t0 = n0; t1 = n1; t2 = n2; t3 = n3; e = en;
            }
        }
        // combine parity halves; pair 0 writes 16 bf16 to s_agg row
        #pragma unroll
        for (int i = 0; i < 16; i++) ga[i] += __shfl_xor(ga[i], 32);
        if (pair == 0) {
            unsigned int pk[8];
            #pragma unroll
            for (int i = 0; i < 8; i++) pk[i] = pk2bf(ga[2 * i], ga[2 * i + 1]);
            uint4* dst = (uint4*)&s_agg[atom * STRA + cw];
            dst[0] = *(uint4*)&pk[0];
            dst[1] = *(uint4*)&pk[4];
        }

        __syncthreads();   // agg complete; hx reads done (s_t alias safe)

        // ---- GEMM2: t = ssp(agg @ cf2 + b) ----
        float bva[2], bvb[2];
        #pragma unroll
        for (int nt = 0; nt < 2; nt++) {
            bva[nt] = cf2_b[l * 128 + c32 + nt * 16 + l15];
            bvb[nt] = lin_b[l * 128 + c32 + nt * 16 + l15];
        }
        #pragma unroll
        for (int nt = 0; nt < 2; nt++) acc[nt] = (floatx4){0.f, 0.f, 0.f, 0.f};
        #pragma unroll
        for (int ks = 0; ks < 4; ks++) {
            short8 af = *(const short8*)&s_agg[(r16 + l15) * STRA + ks * 32 + quad * 8];
            #pragma unroll
            for (int nt = 0; nt < 2; nt++) {
                short8 bfg = *(const short8*)&W2[(size_t)(c32 + nt * 16 + l15) * 128 + ks * 32 + quad * 8];
                acc[nt] = __builtin_amdgcn_mfma_f32_16x16x32_bf16(af, bfg, acc[nt], 0, 0, 0);
            }
        }
        #pragma unroll
        for (int nt = 0; nt < 2; nt++) {
            #pragma unroll
            for (int r = 0; r < 4; r++) {
                int row = r16 + quad * 4 + r;
                s_t[row * STRA + c32 + nt * 16 + l15] = f2bf(ssp(acc[nt][r] + bva[nt]));
            }
        }

        __syncthreads();   // t complete (cross-wave cols needed by GEMM3)

        // ---- GEMM3: h += t @ lin + b ----
        #pragma unroll
        for (int nt = 0; nt < 2; nt++) acc[nt] = (floatx4){0.f, 0.f, 0.f, 0.f};
        #pragma unroll
        for (int ks = 0; ks < 4; ks++) {
            short8 af = *(const short8*)&s_t[(r16 + l15) * STRA + ks * 32 + quad * 8];
            #pragma unroll
            for (int nt = 0; nt < 2; nt++) {
                short8 bfg = *(const short8*)&W3[(size_t)(c32 + nt * 16 + l15) * 128 + ks * 32 + quad * 8];
                acc[nt] = __builtin_amdgcn_mfma_f32_16x16x32_bf16(af, bfg, acc[nt], 0, 0, 0);
            }
        }
        #pragma unroll
        for (int nt = 0; nt < 2; nt++) {
            #pragma unroll
            for (int r = 0; r < 4; r++) {
                int row = r16 + quad * 4 + r;
                s_h[row * STRH + c32 + nt * 16 + l15] += acc[nt][r] + bvb[nt];
            }
        }
        // loop-top __syncthreads covers h
    }

    __syncthreads();

    // ---- head: out = sum_a ssp(h@out1 + b1)@out2 + 32*b2 ----
    const int c16 = (w >> 1) * 16;   // out1: 64 cols = 4 col tiles x 2 row tiles
    floatx4 ha = (floatx4){0.f, 0.f, 0.f, 0.f};
    #pragma unroll
    for (int ks = 0; ks < 4; ks++) {
        const float* hp = &s_h[(r16 + l15) * STRH + ks * 32 + quad * 8];
        float4 xa = *(const float4*)hp;
        float4 xb = *(const float4*)(hp + 4);
        unsigned int ap[4];
        ap[0] = pk2bf(xa.x, xa.y); ap[1] = pk2bf(xa.z, xa.w);
        ap[2] = pk2bf(xb.x, xb.y); ap[3] = pk2bf(xb.z, xb.w);
        short8 af;
        __builtin_memcpy(&af, ap, 16);
        short8 bfg = *(const short8*)&WtO[(size_t)(c16 + l15) * 128 + ks * 32 + quad * 8];
        ha = __builtin_amdgcn_mfma_f32_16x16x32_bf16(af, bfg, ha, 0, 0, 0);
    }
    float part = 0.0f;
    {
        float b1o = out1_b[c16 + l15];
        float o2  = out2_w[c16 + l15];
        #pragma unroll
        for (int r = 0; r < 4; r++)
            part += ssp(ha[r] + b1o) * o2;
    }
    #pragma unroll
    for (int off = 32; off > 0; off >>= 1) part += __shfl_down(part, off);
    if (lane == 0) atomicAdd(&s_red, part);
    __syncthreads();
    if (tid == 0) out[blockIdx.x] = s_red + 32.0f * out2_b[0];
}

extern "C" void kernel_launch(void* const* d_in, const int* in_sizes, int n_in,
                              void* d_out, int out_size, void* d_ws, size_t ws_size,
                              hipStream_t stream)
{
    const int*   z      = (const int*)d_in[0];
    const float* pos    = (const float*)d_in[1];
    const int*   eidx   = (const int*)d_in[3];
    const float* emb    = (const float*)d_in[4];
    const float* mlp_w1 = (const float*)d_in[5];
    const float* mlp_b1 = (const float*)d_in[6];
    const float* mlp_w2 = (const float*)d_in[7];
    const float* mlp_b2 = (const float*)d_in[8];
    const float* cf1_w  = (const float*)d_in[9];
    const float* cf2_w  = (const float*)d_in[10];
    const float* cf2_b  = (const float*)d_in[11];
    const float* lin_w  = (const float*)d_in[12];
    const float* lin_b  = (const float*)d_in[13];
    const float* out1_w = (const float*)d_in[14];
    const float* out1_b = (const float*)d_in[15];
    const float* out2_w = (const float*)d_in[16];
    const float* out2_b = (const float*)d_in[17];
    const int E = in_sizes[3] / 2;

    // workspace carve-up (16B-aligned sections)
    char* p = (char*)d_ws;
    uint2* meta = (uint2*)p;                      p += ((size_t)(E + 1) * 8 + 63) & ~63ULL;
    unsigned int* Tp = (unsigned int*)p;          p += (size_t)3 * KTAB * 128 * 4;
    int* rowptr = (int*)p;                        p += ((size_t)(NATOMS + 1) * 4 + 63) & ~63ULL;
    unsigned short* Wtall = (unsigned short*)p;   // 9*16384 + 64*128 ushorts

    const int EB = (E + NATOMS + 1 + 255) / 256;
    const int WB = (9 * 16384 + 64 * 128 + 255) / 256;
    const int TB = NTILE * 3;
    mega_setup_kernel<<<EB + WB + TB, 256, 0, stream>>>(
        pos, eidx, E, EB, rowptr, cf1_w, cf2_w, lin_w, out1_w, Wtall, meta,
        mlp_w1, mlp_b1, mlp_w2, mlp_b2, Tp);

    fused_schnet_kernel<<<NMOL, 512, 0, stream>>>(
        z, emb, rowptr, meta, Tp, Wtall,
        cf2_b, lin_b, out1_b, out2_w, out2_b, (float*)d_out);
}

// Round 13
// 169.072 us; speedup vs baseline: 1.1815x; 1.1815x over previous
//
#include <hip/hip_runtime.h>
#include <hip/hip_bf16.h>
#include <math.h>

// Problem constants (SchNet reference)
#define NATOMS 16384
#define NMOL   512
#define APM    32
#define GDIM   50
#define KTAB   4096   // filter lookup-table knots over d in [0,6] (nearest-knot)
#define MAXEPM 1000   // max edges per molecule (992) + sentinel

#define STRH 132      // s_h row stride (floats), 528B
#define STRA 136      // s_agg / s_t row stride (ushorts), 272B

typedef __attribute__((ext_vector_type(8))) short   short8;   // 8 bf16 (A/B frag)
typedef __attribute__((ext_vector_type(4))) float   floatx4;  // C/D frag

// fast shifted softplus: log(1+exp(x)) - log2, via HW v_exp_f32/v_log_f32
__device__ __forceinline__ float ssp(float x) {
    float e = __expf(-fabsf(x));
    return fmaxf(x, 0.0f) + __logf(1.0f + e) - 0.69314718055994531f;
}

__device__ __forceinline__ unsigned short f2bf(float x) {
    union { float f; unsigned int u; } v; v.f = x;
    unsigned int lsb = (v.u >> 16) & 1u;
    v.u += 0x7fffu + lsb;
    return (unsigned short)(v.u >> 16);
}

__device__ __forceinline__ unsigned int pk2bf(float a, float b) {
    __hip_bfloat162 h = __float22bfloat162_rn(make_float2(a, b));
    unsigned int u;
    __builtin_memcpy(&u, &h, 4);
    return u;
}

// ---------------------------------------------------------------------------
// MEGA-SETUP (single dispatch, 3 block regions):
//  [0,EB):        per-edge meta {knot<<6 | dst&31} (nearest knot) + rowptr
//  [EB,EB+WB):    weights fp32 -> bf16 B-frag transpose (9x128x128 + out1 64x128)
//  [EB+WB, +192): filter table, 64 tiles x 3 layers, plain bf16 rows:
//                 T[l][k][f] = ((ssp(ea(d_k)@w1+b1)@w2)+b2)*cut(d_k)
// ---------------------------------------------------------------------------
#define KW1 72
#define KW2 136
#define NTILE (KTAB / 64)   // 64 tiles per layer

__global__ __launch_bounds__(256) void mega_setup_kernel(
    const float* __restrict__ pos, const int* __restrict__ eidx, int E, int EB,
    int* __restrict__ rowptr,
    const float* __restrict__ cf1, const float* __restrict__ cf2,
    const float* __restrict__ lin, const float* __restrict__ out1,
    unsigned short* __restrict__ Wtall, unsigned int* __restrict__ meta,
    const float* __restrict__ w1_, const float* __restrict__ b1_,
    const float* __restrict__ w2_, const float* __restrict__ b2_,
    unsigned short* __restrict__ Tt)
{
    const int WB = (9 * 16384 + 64 * 128 + 255) / 256;
    const int b = blockIdx.x;
    const int tid = threadIdx.x;

    if (b < EB) {
        int idx = b * 256 + tid;
        if (idx < E) {
            int s = eidx[idx], t = eidx[E + idx];
            float dx = pos[3 * s]     - pos[3 * t];
            float dy = pos[3 * s + 1] - pos[3 * t + 1];
            float dz = pos[3 * s + 2] - pos[3 * t + 2];
            float d  = sqrtf(dx * dx + dy * dy + dz * dz);
            float u  = d * (float)(KTAB - 1) / 6.0f;
            int i = min((int)(u + 0.5f), KTAB - 1);   // nearest knot
            meta[idx] = ((unsigned)i << 6) | (unsigned)(t & 31);
        } else if (idx < E + NATOMS + 1) {
            int a = idx - E;
            int lo = 0, hi = E;
            while (lo < hi) { int mid = (lo + hi) >> 1; if (eidx[mid] < a) lo = mid + 1; else hi = mid; }
            rowptr[a] = lo;
        }
        return;
    }
    if (b < EB + WB) {
        int idx = (b - EB) * 256 + tid;
        if (idx < 9 * 16384) {
            int wi = idx >> 14, rem = idx & 16383;
            int n = rem >> 7, k = rem & 127;
            int l = wi / 3, which = wi % 3;
            const float* src = (which == 0) ? cf1 : (which == 1) ? cf2 : lin;
            Wtall[idx] = f2bf(src[(size_t)l * 16384 + k * 128 + n]);
        } else if (idx < 9 * 16384 + 64 * 128) {
            int q = idx - 9 * 16384;
            int n = q >> 7, k = q & 127;
            Wtall[idx] = f2bf(out1[k * 64 + n]);
        }
        return;
    }

    // ---------------- table region: tt = (layer, tile) ----------------
    __shared__ unsigned short s_bufA[128 * KW2];   // w2T
    __shared__ unsigned short s_bufB[128 * KW1];   // w1T, then s_t (alias)

    const int tt = b - EB - WB;
    const int l  = tt / NTILE;
    const int bx = tt % NTILE;
    const float* w1 = w1_ + (size_t)l * GDIM * 128;
    const float* b1 = b1_ + (size_t)l * 128;
    const float* w2 = w2_ + (size_t)l * 128 * 128;
    const float* b2 = b2_ + (size_t)l * 128;
    unsigned short* Tg = Tt + (size_t)l * KTAB * 128;

    unsigned short* s_w1T = s_bufB;                // [128][KW1]
    unsigned short* s_w2T = s_bufA;                // [128][KW2]
    unsigned short* s_t   = s_bufB;                // [64][KW2] (after barrier)

    for (int i = tid; i < GDIM * 128; i += 256) {
        int g = i >> 7, f = i & 127;
        s_w1T[f * KW1 + g] = f2bf(w1[i]);
    }
    for (int i = tid; i < (64 - GDIM) * 128; i += 256) {
        int g = GDIM + (i >> 7), f = i & 127;
        s_w1T[f * KW1 + g] = 0;
    }
    for (int i = tid; i < 128 * 128; i += 256) {
        int k = i >> 7, n = i & 127;
        s_w2T[n * KW2 + k] = f2bf(w2[i]);
    }

    const int lane = tid & 63;
    const int w    = tid >> 6;
    const int l15  = lane & 15;
    const int quad = lane >> 4;

    float b1v[8], b2v[8];
    #pragma unroll
    for (int nt = 0; nt < 8; nt++) {
        b1v[nt] = b1[nt * 16 + l15];
        b2v[nt] = b2[nt * 16 + l15];
    }
    __syncthreads();

    const float hstep = 6.0f / (float)(KTAB - 1);
    const float step  = 6.0f / 49.0f;
    const float coeff = -0.5f / (step * step);
    const float pioc  = 3.14159265358979323846f / 6.0f;
    const int k0 = bx * 64;
    const float dm = (float)(k0 + w * 16 + l15) * hstep;

    floatx4 acc1[8];
    #pragma unroll
    for (int nt = 0; nt < 8; nt++) acc1[nt] = (floatx4){0.f, 0.f, 0.f, 0.f};
    #pragma unroll
    for (int ks = 0; ks < 2; ks++) {
        unsigned int ap[4];
        #pragma unroll
        for (int jj = 0; jj < 4; jj++) {
            int g0 = ks * 32 + quad * 8 + 2 * jj;
            float d0 = dm - (float)g0 * step;
            float d1 = dm - (float)(g0 + 1) * step;
            float v0 = (g0 < GDIM)     ? __expf(coeff * d0 * d0) : 0.0f;
            float v1 = (g0 + 1 < GDIM) ? __expf(coeff * d1 * d1) : 0.0f;
            ap[jj] = pk2bf(v0, v1);
        }
        short8 af;
        __builtin_memcpy(&af, ap, 16);
        #pragma unroll
        for (int nt = 0; nt < 8; nt++) {
            short8 bfg = *(const short8*)&s_w1T[(nt * 16 + l15) * KW1 + ks * 32 + quad * 8];
            acc1[nt] = __builtin_amdgcn_mfma_f32_16x16x32_bf16(af, bfg, acc1[nt], 0, 0, 0);
        }
    }
    __syncthreads();   // all waves done reading s_w1T; s_t may alias it

    #pragma unroll
    for (int nt = 0; nt < 8; nt++) {
        #pragma unroll
        for (int r = 0; r < 4; r++) {
            int row = w * 16 + quad * 4 + r;
            s_t[row * KW2 + nt * 16 + l15] = f2bf(ssp(acc1[nt][r] + b1v[nt]));
        }
    }
    // no barrier: wave reads only rows it wrote

    floatx4 acc2[8];
    #pragma unroll
    for (int nt = 0; nt < 8; nt++) acc2[nt] = (floatx4){0.f, 0.f, 0.f, 0.f};
    #pragma unroll
    for (int ks = 0; ks < 4; ks++) {
        short8 af = *(const short8*)&s_t[(w * 16 + l15) * KW2 + ks * 32 + quad * 8];
        #pragma unroll
        for (int nt = 0; nt < 8; nt++) {
            short8 bfg = *(const short8*)&s_w2T[(nt * 16 + l15) * KW2 + ks * 32 + quad * 8];
            acc2[nt] = __builtin_amdgcn_mfma_f32_16x16x32_bf16(af, bfg, acc2[nt], 0, 0, 0);
        }
    }

    #pragma unroll
    for (int nt = 0; nt < 8; nt++) {
        #pragma unroll
        for (int r = 0; r < 4; r++) {
            int row = w * 16 + quad * 4 + r;
            float d = (float)(k0 + row) * hstep;
            float cut = 0.5f * (__cosf(d * pioc) + 1.0f);
            Tg[(size_t)(k0 + row) * 128 + nt * 16 + l15] = f2bf((acc2[nt][r] + b2v[nt]) * cut);
        }
    }
}

// ---------------------------------------------------------------------------
// Fully-fused SchNet: one block = one molecule, 512 threads = 8 waves.
// GEMM tile per wave: rows (w&1)*16, cols (w>>1)*32.
// Gather (R8-proven shape): wave serially covers 4 atoms, lane = 2 channels,
// 8-deep unrolled edge batches; nearest-knot plain-bf16 table (1 uint load =
// 2 channels, no lerp); sentinel edge -> zero hx row kills loop tails.
// ---------------------------------------------------------------------------
__global__ __launch_bounds__(512, 4) void fused_schnet_kernel(
    const int* __restrict__ z, const float* __restrict__ emb,
    const int* __restrict__ rowptr, const unsigned int* __restrict__ meta,
    const unsigned short* __restrict__ Tt,
    const unsigned short* __restrict__ Wtall,
    const float* __restrict__ cf2_b, const float* __restrict__ lin_b,
    const float* __restrict__ out1_b, const float* __restrict__ out2_w,
    const float* __restrict__ out2_b,
    float* __restrict__ out)
{
    __shared__ float s_h[32 * STRH];                 // 16.9 KB fp32 node state
    __shared__ float s_hx[33 * 128];                 // 16.9 KB; row 32 = zeros
    __shared__ unsigned short s_agg[32 * STRA];      //  8.7 KB bf16
    __shared__ unsigned int s_meta[MAXEPM];          //  4.0 KB
    __shared__ float s_red;
    unsigned short* s_t = (unsigned short*)s_hx;     // [32][STRA] alias (8.7KB)

    const int tid  = threadIdx.x;
    const int lane = tid & 63;
    const int w    = tid >> 6;          // wave 0..7
    const int l15  = lane & 15;
    const int quad = lane >> 4;
    const int r16  = (w & 1) * 16;      // GEMM row tile
    const int c32  = (w >> 1) * 32;     // GEMM col tile
    const int B0   = blockIdx.x * 32;   // molecule base atom

    // init h; zero hx dummy row
    for (int i = tid; i < 32 * 128; i += 512) {
        int row = i >> 7, col = i & 127;
        s_h[row * STRH + col] = emb[(size_t)z[B0 + row] * 128 + col];
    }
    if (tid < 128) s_hx[32 * 128 + tid] = 0.0f;
    if (tid == 0) s_red = 0.0f;

    // stage edge metadata + sentinel (knot 0, zero row 32)
    const int ebase = rowptr[B0];
    const int nE    = rowptr[B0 + 32] - ebase;
    for (int i = tid; i < nE; i += 512) s_meta[i] = meta[ebase + i];
    if (tid == 0) s_meta[nE] = 32u;

    // local row pointers for this wave's 4 atoms (5 bounds in lanes 0..4)
    const int rp = rowptr[B0 + w * 4 + min(lane, 4)] - ebase;

    const unsigned short* WtO = Wtall + 9 * 16384;   // out1^T

    for (int l = 0; l < 3; l++) {
        const unsigned short* W1 = Wtall + (size_t)(l * 3 + 0) * 16384;
        const unsigned short* W2 = Wtall + (size_t)(l * 3 + 1) * 16384;
        const unsigned short* W3 = Wtall + (size_t)(l * 3 + 2) * 16384;
        const unsigned short* Ttl = Tt + (size_t)l * KTAB * 128;

        __syncthreads();   // h ready (also covers init/meta staging at l=0)

        // ---- GEMM1: hx = h @ cf1 (16x32 tile per wave) ----
        floatx4 acc[2];
        #pragma unroll
        for (int nt = 0; nt < 2; nt++) acc[nt] = (floatx4){0.f, 0.f, 0.f, 0.f};
        #pragma unroll
        for (int ks = 0; ks < 4; ks++) {
            const float* hp = &s_h[(r16 + l15) * STRH + ks * 32 + quad * 8];
            float4 xa = *(const float4*)hp;
            float4 xb = *(const float4*)(hp + 4);
            unsigned int ap[4];
            ap[0] = pk2bf(xa.x, xa.y); ap[1] = pk2bf(xa.z, xa.w);
            ap[2] = pk2bf(xb.x, xb.y); ap[3] = pk2bf(xb.z, xb.w);
            short8 af;
            __builtin_memcpy(&af, ap, 16);
            #pragma unroll
            for (int nt = 0; nt < 2; nt++) {
                short8 bfg = *(const short8*)&W1[(size_t)(c32 + nt * 16 + l15) * 128 + ks * 32 + quad * 8];
                acc[nt] = __builtin_amdgcn_mfma_f32_16x16x32_bf16(af, bfg, acc[nt], 0, 0, 0);
            }
        }
        #pragma unroll
        for (int nt = 0; nt < 2; nt++) {
            #pragma unroll
            for (int r = 0; r < 4; r++)
                s_hx[(r16 + quad * 4 + r) * 128 + c32 + nt * 16 + l15] = acc[nt][r];
        }

        __syncthreads();   // hx complete before gather reads

        // ---- gather: wave per 4 atoms, 2 channels/lane, nearest-knot ----
        for (int al = 0; al < 4; al++) {
            const int e0 = __shfl(rp, al);
            const int e1 = __shfl(rp, al + 1);
            float ax[8], ay[8];
            #pragma unroll
            for (int j = 0; j < 8; j++) { ax[j] = 0.f; ay[j] = 0.f; }
            for (int e = e0; e < e1; e += 8) {
                #pragma unroll
                for (int j = 0; j < 8; j++) {
                    int idx = (e + j < e1) ? (e + j) : nE;   // sentinel
                    unsigned int q = s_meta[idx];
                    int tl   = q & 63;
                    int knot = q >> 6;
                    unsigned int tp = *(const unsigned int*)&Ttl[((size_t)knot << 7) + 2 * lane];
                    float2 hv = *(const float2*)&s_hx[(tl << 7) + 2 * lane];
                    ax[j] = fmaf(hv.x, __uint_as_float(tp << 16), ax[j]);
                    ay[j] = fmaf(hv.y, __uint_as_float(tp & 0xffff0000u), ay[j]);
                }
            }
            float sx = ((ax[0] + ax[1]) + (ax[2] + ax[3])) + ((ax[4] + ax[5]) + (ax[6] + ax[7]));
            float sy = ((ay[0] + ay[1]) + (ay[2] + ay[3])) + ((ay[4] + ay[5]) + (ay[6] + ay[7]));
            *(unsigned int*)&s_agg[(w * 4 + al) * STRA + 2 * lane] = pk2bf(sx, sy);
        }

        __syncthreads();   // agg complete; hx reads done (s_t alias safe)

        // ---- GEMM2: t = ssp(agg @ cf2 + b) ----
        float bva[2], bvb[2];
        #pragma unroll
        for (int nt = 0; nt < 2; nt++) {
            bva[nt] = cf2_b[l * 128 + c32 + nt * 16 + l15];
            bvb[nt] = lin_b[l * 128 + c32 + nt * 16 + l15];
        }
        #pragma unroll
        for (int nt = 0; nt < 2; nt++) acc[nt] = (floatx4){0.f, 0.f, 0.f, 0.f};
        #pragma unroll
        for (int ks = 0; ks < 4; ks++) {
            short8 af = *(const short8*)&s_agg[(r16 + l15) * STRA + ks * 32 + quad * 8];
            #pragma unroll
            for (int nt = 0; nt < 2; nt++) {
                short8 bfg = *(const short8*)&W2[(size_t)(c32 + nt * 16 + l15) * 128 + ks * 32 + quad * 8];
                acc[nt] = __builtin_amdgcn_mfma_f32_16x16x32_bf16(af, bfg, acc[nt], 0, 0, 0);
            }
        }
        #pragma unroll
        for (int nt = 0; nt < 2; nt++) {
            #pragma unroll
            for (int r = 0; r < 4; r++) {
                int row = r16 + quad * 4 + r;
                s_t[row * STRA + c32 + nt * 16 + l15] = f2bf(ssp(acc[nt][r] + bva[nt]));
            }
        }

        __syncthreads();   // t complete (cross-wave cols needed by GEMM3)

        // ---- GEMM3: h += t @ lin + b ----
        #pragma unroll
        for (int nt = 0; nt < 2; nt++) acc[nt] = (floatx4){0.f, 0.f, 0.f, 0.f};
        #pragma unroll
        for (int ks = 0; ks < 4; ks++) {
            short8 af = *(const short8*)&s_t[(r16 + l15) * STRA + ks * 32 + quad * 8];
            #pragma unroll
            for (int nt = 0; nt < 2; nt++) {
                short8 bfg = *(const short8*)&W3[(size_t)(c32 + nt * 16 + l15) * 128 + ks * 32 + quad * 8];
                acc[nt] = __builtin_amdgcn_mfma_f32_16x16x32_bf16(af, bfg, acc[nt], 0, 0, 0);
            }
        }
        #pragma unroll
        for (int nt = 0; nt < 2; nt++) {
            #pragma unroll
            for (int r = 0; r < 4; r++) {
                int row = r16 + quad * 4 + r;
                s_h[row * STRH + c32 + nt * 16 + l15] += acc[nt][r] + bvb[nt];
            }
        }
        // loop-top __syncthreads covers h
    }

    __syncthreads();

    // ---- head: out = sum_a ssp(h@out1 + b1)@out2 + 32*b2 ----
    const int c16 = (w >> 1) * 16;   // out1: 64 cols = 4 col tiles x 2 row tiles
    floatx4 ha = (floatx4){0.f, 0.f, 0.f, 0.f};
    #pragma unroll
    for (int ks = 0; ks < 4; ks++) {
        const float* hp = &s_h[(r16 + l15) * STRH + ks * 32 + quad * 8];
        float4 xa = *(const float4*)hp;
        float4 xb = *(const float4*)(hp + 4);
        unsigned int ap[4];
        ap[0] = pk2bf(xa.x, xa.y); ap[1] = pk2bf(xa.z, xa.w);
        ap[2] = pk2bf(xb.x, xb.y); ap[3] = pk2bf(xb.z, xb.w);
        short8 af;
        __builtin_memcpy(&af, ap, 16);
        short8 bfg = *(const short8*)&WtO[(size_t)(c16 + l15) * 128 + ks * 32 + quad * 8];
        ha = __builtin_amdgcn_mfma_f32_16x16x32_bf16(af, bfg, ha, 0, 0, 0);
    }
    float part = 0.0f;
    {
        float b1o = out1_b[c16 + l15];
        float o2  = out2_w[c16 + l15];
        #pragma unroll
        for (int r = 0; r < 4; r++)
            part += ssp(ha[r] + b1o) * o2;
    }
    #pragma unroll
    for (int off = 32; off > 0; off >>= 1) part += __shfl_down(part, off);
    if (lane == 0) atomicAdd(&s_red, part);
    __syncthreads();
    if (tid == 0) out[blockIdx.x] = s_red + 32.0f * out2_b[0];
}

extern "C" void kernel_launch(void* const* d_in, const int* in_sizes, int n_in,
                              void* d_out, int out_size, void* d_ws, size_t ws_size,
                              hipStream_t stream)
{
    const int*   z      = (const int*)d_in[0];
    const float* pos    = (const float*)d_in[1];
    const int*   eidx   = (const int*)d_in[3];
    const float* emb    = (const float*)d_in[4];
    const float* mlp_w1 = (const float*)d_in[5];
    const float* mlp_b1 = (const float*)d_in[6];
    const float* mlp_w2 = (const float*)d_in[7];
    const float* mlp_b2 = (const float*)d_in[8];
    const float* cf1_w  = (const float*)d_in[9];
    const float* cf2_w  = (const float*)d_in[10];
    const float* cf2_b  = (const float*)d_in[11];
    const float* lin_w  = (const float*)d_in[12];
    const float* lin_b  = (const float*)d_in[13];
    const float* out1_w = (const float*)d_in[14];
    const float* out1_b = (const float*)d_in[15];
    const float* out2_w = (const float*)d_in[16];
    const float* out2_b = (const float*)d_in[17];
    const int E = in_sizes[3] / 2;

    // workspace carve-up (16B-aligned sections)
    char* p = (char*)d_ws;
    unsigned int* meta = (unsigned int*)p;        p += ((size_t)(E + 1) * 4 + 63) & ~63ULL;
    unsigned short* Tt = (unsigned short*)p;      p += (size_t)3 * KTAB * 128 * 2;
    int* rowptr = (int*)p;                        p += ((size_t)(NATOMS + 1) * 4 + 63) & ~63ULL;
    unsigned short* Wtall = (unsigned short*)p;   // 9*16384 + 64*128 ushorts

    const int EB = (E + NATOMS + 1 + 255) / 256;
    const int WB = (9 * 16384 + 64 * 128 + 255) / 256;
    const int TB = NTILE * 3;
    mega_setup_kernel<<<EB + WB + TB, 256, 0, stream>>>(
        pos, eidx, E, EB, rowptr, cf1_w, cf2_w, lin_w, out1_w, Wtall, meta,
        mlp_w1, mlp_b1, mlp_w2, mlp_b2, Tt);

    fused_schnet_kernel<<<NMOL, 512, 0, stream>>>(
        z, emb, rowptr, meta, Tt, Wtall,
        cf2_b, lin_b, out1_b, out2_w, out2_b, (float*)d_out);
}